// Round 3
// baseline (892.256 us; speedup 1.0000x reference)
//
#include <hip/hip_runtime.h>
#include <hip/hip_bf16.h>

// MambaLM: B=2,K=4,T=1024,V=1024, d_model=512, d_inner=1024, N=16, dt_rank=32, L=2
// Round 3: inputs f32 (confirmed: bf16-read gave NaN, f32-read gave finite right-scale),
// output f32 (harness doc: reference output dtype f32 -> float*; R2's packed-u16
// write produced the exact decorrelated-right-scale + half-zero error signature).

#define B_SZ 2
#define K_CB 4
#define T_SZ 1024
#define V_SZ 1024
#define DM 512
#define DI 1024
#define NS 16
#define DTR 32
#define NCHUNK 16
#define TCHUNK 64

typedef long long ll;

__device__ __forceinline__ float siluf(float x) { return x / (1.f + expf(-x)); }
__device__ __forceinline__ float softplusf(float x) { return (x > 20.f) ? x : log1pf(expf(x)); }

// ---------------- embedding: x[b,t,d] = sum_k embed_w[k, codes[b,k,t], d] ----------------
__global__ __launch_bounds__(512) void embed_k(const int* __restrict__ codes,
                                               const float* __restrict__ ew,
                                               float* __restrict__ x) {
    int row = blockIdx.x;           // b*1024 + t
    int b = row >> 10, t = row & 1023;
    int d = threadIdx.x;            // 0..511
    float acc = 0.f;
#pragma unroll
    for (int k = 0; k < K_CB; k++) {
        int c = codes[b * (K_CB * T_SZ) + k * T_SZ + t];
        acc += ew[((ll)k * V_SZ + c) * DM + d];
    }
    x[(ll)row * DM + d] = acc;
}

// ---------------- rmsnorm ----------------
__global__ __launch_bounds__(256) void rmsnorm_k(const float* __restrict__ x,
                                                 const float* __restrict__ w,
                                                 float* __restrict__ xn) {
    ll row = blockIdx.x;
    const float* xr = x + row * DM;
    int tid = threadIdx.x;
    float v0 = xr[tid], v1 = xr[tid + 256];
    float ss = v0 * v0 + v1 * v1;
#pragma unroll
    for (int off = 32; off > 0; off >>= 1) ss += __shfl_down(ss, off, 64);
    __shared__ float red[4];
    if ((tid & 63) == 0) red[tid >> 6] = ss;
    __syncthreads();
    float tot = red[0] + red[1] + red[2] + red[3];
    float scale = rsqrtf(tot * (1.0f / DM) + 1e-6f);
    xn[row * DM + tid]       = v0 * scale * w[tid];
    xn[row * DM + tid + 256] = v1 * scale * w[tid + 256];
}

// ---------------- tiled f32 GEMM: C[M,N] = A[M,K] * W^T (W is [N,K] f32) ----------------
// EP: 0 = plain f32 store, 1 = softplus(acc + bias[n]), 2 = C += acc (residual),
//     3 = head: f32 scatter out[b, kcb, t, v]
// BKN: if true, W is [K,N] layout (row stride ldw) -- used for head (head_w[k] is (D,V)).
template <int EP, bool BKN>
__global__ __launch_bounds__(256) void gemm_k(const float* __restrict__ A, int lda,
                                              const float* __restrict__ W, int ldw,
                                              float* __restrict__ C, int ldc,
                                              int M, int N, int K,
                                              const float* __restrict__ bias,
                                              float* __restrict__ Cb, ll cb_base) {
    __shared__ float As[16][64];
    __shared__ float Bs[16][64];
    int tid = threadIdx.x;
    int m0 = blockIdx.y * 64, n0 = blockIdx.x * 64;
    int ty = tid >> 4, tx = tid & 15;
    float acc[4][4] = {};

    for (int k0 = 0; k0 < K; k0 += 16) {
        // stage A tile (64x16 f32): one float4 per thread
        {
            int m = tid >> 2;
            int k4 = (tid & 3) << 2;
            const float4 av = *(const float4*)&A[(ll)(m0 + m) * lda + k0 + k4];
            As[k4 + 0][m] = av.x; As[k4 + 1][m] = av.y;
            As[k4 + 2][m] = av.z; As[k4 + 3][m] = av.w;
        }
        // stage W tile -> Bs[k][n]
        if (BKN) {
            int k = tid >> 4;
            int n4 = (tid & 15) << 2;
            const float4 wv = *(const float4*)&W[(ll)(k0 + k) * ldw + n0 + n4];
            *(float4*)&Bs[k][n4] = wv;
        } else {
            int n = tid >> 2;
            int k4 = (tid & 3) << 2;
            const float4 wv = *(const float4*)&W[(ll)(n0 + n) * ldw + k0 + k4];
            Bs[k4 + 0][n] = wv.x; Bs[k4 + 1][n] = wv.y;
            Bs[k4 + 2][n] = wv.z; Bs[k4 + 3][n] = wv.w;
        }
        __syncthreads();
#pragma unroll
        for (int k = 0; k < 16; k++) {
            float4 a4 = *(const float4*)&As[k][ty << 2];
            float4 b4 = *(const float4*)&Bs[k][tx << 2];
            float av[4] = {a4.x, a4.y, a4.z, a4.w};
            float bv[4] = {b4.x, b4.y, b4.z, b4.w};
#pragma unroll
            for (int i = 0; i < 4; i++)
#pragma unroll
                for (int j = 0; j < 4; j++)
                    acc[i][j] = fmaf(av[i], bv[j], acc[i][j]);
        }
        __syncthreads();
    }

#pragma unroll
    for (int i = 0; i < 4; i++) {
        int m = m0 + (ty << 2) + i;
        int n = n0 + (tx << 2);
        if (EP == 0) {
            float4 v; v.x = acc[i][0]; v.y = acc[i][1]; v.z = acc[i][2]; v.w = acc[i][3];
            *(float4*)&C[(ll)m * ldc + n] = v;
        } else if (EP == 1) {
            float4 v;
            v.x = softplusf(acc[i][0] + bias[n + 0]);
            v.y = softplusf(acc[i][1] + bias[n + 1]);
            v.z = softplusf(acc[i][2] + bias[n + 2]);
            v.w = softplusf(acc[i][3] + bias[n + 3]);
            *(float4*)&C[(ll)m * ldc + n] = v;
        } else if (EP == 2) {
            float4* p = (float4*)&C[(ll)m * ldc + n];
            float4 old = *p;
            old.x += acc[i][0]; old.y += acc[i][1]; old.z += acc[i][2]; old.w += acc[i][3];
            *p = old;
        } else {
            int b = m >> 10, t = m & 1023;
            ll o = (ll)b * (K_CB * (ll)T_SZ * V_SZ) + cb_base + (ll)t * V_SZ + n;
            float4 v; v.x = acc[i][0]; v.y = acc[i][1]; v.z = acc[i][2]; v.w = acc[i][3];
            *(float4*)&Cb[o] = v;
        }
    }
}

// ---------------- causal depthwise conv (d_conv=4) + bias + silu ----------------
__global__ __launch_bounds__(256) void conv_k(const float* __restrict__ xz,
                                              const float* __restrict__ cw,
                                              const float* __restrict__ cb,
                                              float* __restrict__ xc) {
    int row = blockIdx.x;        // b*1024+t
    int b = row >> 10, t = row & 1023;
    for (int c = threadIdx.x; c < DI; c += 256) {
        float acc = cb[c];
#pragma unroll
        for (int j = 0; j < 4; j++) {
            int tt = t - 3 + j;
            if (tt >= 0)
                acc += xz[((ll)(b * T_SZ + tt)) * (2 * DI) + c] * cw[c * 4 + j];
        }
        xc[(ll)row * DI + c] = siluf(acc);
    }
}

// ---------------- chunked selective scan, pass 1: per-chunk (prodA, U) ----------------
// grid: B * NCHUNK * (DI/256) = 2*16*4 = 128 blocks
__global__ __launch_bounds__(256) void scan1_k(const float* __restrict__ dt,
                                               const float* __restrict__ xc,
                                               const float* __restrict__ xdbl,
                                               const float* __restrict__ A_log,
                                               float* __restrict__ pA, float* __restrict__ U) {
    int blk = blockIdx.x;
    int dblk = blk & 3;
    int c = (blk >> 2) & 15;
    int b = blk >> 6;
    int d = dblk * 256 + threadIdx.x;
    float Av[NS];
#pragma unroll
    for (int n = 0; n < NS; n++) Av[n] = -expf(A_log[d * NS + n]);
    float p[NS], u[NS];
#pragma unroll
    for (int n = 0; n < NS; n++) { p[n] = 1.f; u[n] = 0.f; }
    int t0 = c * TCHUNK;
    for (int s = 0; s < TCHUNK; s++) {
        ll ro = (ll)b * T_SZ + t0 + s;
        float dtv = dt[ro * DI + d];
        float xv = xc[ro * DI + d];
        float dx = dtv * xv;
        const float* Brow = xdbl + ro * 64 + DTR;
#pragma unroll
        for (int n = 0; n < NS; n++) {
            float a = expf(dtv * Av[n]);
            p[n] *= a;
            u[n] = fmaf(a, u[n], dx * Brow[n]);
        }
    }
    ll o = (((ll)b * NCHUNK + c) * DI + d) * NS;
#pragma unroll
    for (int n = 0; n < NS; n++) { pA[o + n] = p[n]; U[o + n] = u[n]; }
}

// pass 2: sequential combine over chunks, store h at chunk starts
__global__ __launch_bounds__(256) void scan2_k(const float* __restrict__ pA,
                                               const float* __restrict__ U,
                                               float* __restrict__ hst) {
    int i = blockIdx.x * 256 + threadIdx.x;   // b*(DI*NS) + d*NS + n
    int b = i >> 14;
    int rest = i & 16383;
    float h = 0.f;
#pragma unroll
    for (int c = 0; c < NCHUNK; c++) {
        ll o = ((ll)b * NCHUNK + c) * (DI * NS) + rest;
        hst[o] = h;
        h = fmaf(pA[o], h, U[o]);
    }
}

// pass 3: replay chunk with true initial h; fuse D_skip and silu(z) gate
__global__ __launch_bounds__(256) void scan3_k(const float* __restrict__ dt,
                                               const float* __restrict__ xc,
                                               const float* __restrict__ xdbl,
                                               const float* __restrict__ xz,
                                               const float* __restrict__ A_log,
                                               const float* __restrict__ Dk,
                                               const float* __restrict__ hst,
                                               float* __restrict__ y) {
    int blk = blockIdx.x;
    int dblk = blk & 3;
    int c = (blk >> 2) & 15;
    int b = blk >> 6;
    int d = dblk * 256 + threadIdx.x;
    float Av[NS];
#pragma unroll
    for (int n = 0; n < NS; n++) Av[n] = -expf(A_log[d * NS + n]);
    float h[NS];
    ll ho = (((ll)b * NCHUNK + c) * DI + d) * NS;
#pragma unroll
    for (int n = 0; n < NS; n++) h[n] = hst[ho + n];
    float Dv = Dk[d];
    int t0 = c * TCHUNK;
    for (int s = 0; s < TCHUNK; s++) {
        ll ro = (ll)b * T_SZ + t0 + s;
        float dtv = dt[ro * DI + d];
        float xv = xc[ro * DI + d];
        float dx = dtv * xv;
        const float* Brow = xdbl + ro * 64 + DTR;
        const float* Crow = xdbl + ro * 64 + DTR + NS;
        float acc = 0.f;
#pragma unroll
        for (int n = 0; n < NS; n++) {
            float a = expf(dtv * Av[n]);
            h[n] = fmaf(a, h[n], dx * Brow[n]);
            acc = fmaf(h[n], Crow[n], acc);
        }
        float zv = xz[ro * (2 * DI) + DI + d];
        y[ro * DI + d] = (acc + xv * Dv) * siluf(zv);
    }
}

extern "C" void kernel_launch(void* const* d_in, const int* in_sizes, int n_in,
                              void* d_out, int out_size, void* d_ws, size_t ws_size,
                              hipStream_t stream) {
    const int*   codes   = (const int*)d_in[0];
    const float* embed_w = (const float*)d_in[1];
    const float* norm_w  = (const float*)d_in[2];
    const float* in_w    = (const float*)d_in[3];
    const float* conv_w  = (const float*)d_in[4];
    const float* conv_b  = (const float*)d_in[5];
    const float* xp_w    = (const float*)d_in[6];
    const float* dtp_w   = (const float*)d_in[7];
    const float* dtp_b   = (const float*)d_in[8];
    const float* A_log   = (const float*)d_in[9];
    const float* D_skip  = (const float*)d_in[10];
    const float* out_w   = (const float*)d_in[11];
    const float* head_w  = (const float*)d_in[12];
    float* out = (float*)d_out;

    float* ws = (float*)d_ws;
    float* x    = ws;                    // 2048*512          (4 MB)
    float* xz   = x + 1048576;           // 2048*2048         (16 MB)
    float* xc   = xz + 4194304;          // 2048*1024         (8 MB)
    float* dtb  = xc + 2097152;          // 2048*1024         (8 MB)
    float* ybxn = dtb + 2097152;         // 2048*1024 shared  (8 MB): xn uses first half
    float* xdbl = ybxn + 2097152;        // 2048*64           (0.5 MB)
    float* pA   = xdbl + 131072;         // 2*16*1024*16      (2 MB)
    float* Ub   = pA + 524288;           // (2 MB)
    float* hst  = Ub + 524288;           // (2 MB)  total ~50.5 MB

    float* xn = ybxn;                    // alias: lifetimes disjoint within a layer
    float* yb = ybxn;

    const int M = B_SZ * T_SZ;           // 2048

    embed_k<<<M, 512, 0, stream>>>(codes, embed_w, x);

    for (int l = 0; l < 2; l++) {
        const float* nw  = norm_w + l * DM;
        const float* iw  = in_w + (ll)l * (2 * DI) * DM;
        const float* cw  = conv_w + l * DI * 4;
        const float* cb  = conv_b + l * DI;
        const float* xpw = xp_w + (ll)l * 64 * DI;
        const float* dw  = dtp_w + (ll)l * DI * DTR;
        const float* db  = dtp_b + l * DI;
        const float* al  = A_log + l * DI * NS;
        const float* dsk = D_skip + l * DI;
        const float* ow  = out_w + (ll)l * DM * DI;

        rmsnorm_k<<<M, 256, 0, stream>>>(x, nw, xn);
        // xz = xn @ in_w^T : (2048 x 2048), K=512
        gemm_k<0, false><<<dim3(32, 32), 256, 0, stream>>>(xn, DM, iw, DM, xz, 2 * DI,
                                                           M, 2 * DI, DM, nullptr, nullptr, 0);
        conv_k<<<M, 256, 0, stream>>>(xz, cw, cb, xc);
        // x_dbl = xc @ xp_w^T : (2048 x 64), K=1024
        gemm_k<0, false><<<dim3(1, 32), 256, 0, stream>>>(xc, DI, xpw, DI, xdbl, 64,
                                                          M, 64, DI, nullptr, nullptr, 0);
        // dt = softplus(x_dbl[:, :32] @ dtp_w^T + b) : (2048 x 1024), K=32
        gemm_k<1, false><<<dim3(16, 32), 256, 0, stream>>>(xdbl, 64, dw, DTR, dtb, DI,
                                                           M, DI, DTR, db, nullptr, 0);
        scan1_k<<<128, 256, 0, stream>>>(dtb, xc, xdbl, al, pA, Ub);
        scan2_k<<<128, 256, 0, stream>>>(pA, Ub, hst);
        scan3_k<<<128, 256, 0, stream>>>(dtb, xc, xdbl, xz, al, dsk, hst, yb);
        // x += y @ out_w^T : (2048 x 512), K=1024
        gemm_k<2, false><<<dim3(8, 32), 256, 0, stream>>>(yb, DI, ow, DI, x, DM,
                                                          M, DM, DI, nullptr, nullptr, 0);
    }

    // head: out[b,k,t,v] = sum_d x[b,t,d] * head_w[k,d,v]  (head_w[k] is (512,1024), [K,N])
    for (int k = 0; k < K_CB; k++) {
        gemm_k<3, true><<<dim3(16, 32), 256, 0, stream>>>(x, DM, head_w + (ll)k * DM * V_SZ, V_SZ,
                                                          nullptr, 0, M, V_SZ, DM,
                                                          nullptr, out, (ll)k * T_SZ * V_SZ);
    }
}

// Round 4
// 349.049 us; speedup vs baseline: 2.5562x; 2.5562x over previous
//
#include <hip/hip_runtime.h>
#include <hip/hip_bf16.h>

// MambaLM: B=2,K=4,T=1024,V=1024, d_model=512, d_inner=1024, N=16, dt_rank=32, L=2
// R4: (1) scans TCHUNK 64->16 (4x occupancy) + __expf;
//     (2) all big GEMMs -> bf16 MFMA 16x16x32, f32 accumulate, 64x64 tiles.

#define B_SZ 2
#define K_CB 4
#define T_SZ 1024
#define V_SZ 1024
#define DM 512
#define DI 1024
#define NS 16
#define DTR 32
#define NCHUNK 64
#define TCHUNK 16

typedef unsigned short u16;
typedef long long ll;
using short8 = __attribute__((ext_vector_type(8))) short;
using f32x4  = __attribute__((ext_vector_type(4))) float;

__device__ __forceinline__ float bf2f(u16 u) {
    union { unsigned int i; float f; } v; v.i = ((unsigned int)u) << 16; return v.f;
}
__device__ __forceinline__ u16 f2bf(float f) {
    union { float f; unsigned int i; } v; v.f = f;
    unsigned int x = v.i;
    return (u16)((x + 0x7fffu + ((x >> 16) & 1u)) >> 16);
}
__device__ __forceinline__ float siluf(float x) { return x / (1.f + __expf(-x)); }
__device__ __forceinline__ float softplusf(float x) { return (x > 20.f) ? x : log1pf(__expf(x)); }

// ---------------- weight bf16 conversion (4 flat regions, one launch) ----------------
__global__ __launch_bounds__(256) void wcvt_k(const float* __restrict__ a, u16* __restrict__ da, int na,
                                              const float* __restrict__ b2, u16* __restrict__ db, int nb,
                                              const float* __restrict__ c, u16* __restrict__ dc, int nc,
                                              const float* __restrict__ d, u16* __restrict__ dd) {
    int i = blockIdx.x * 256 + threadIdx.x;
    if (i < na) { da[i] = f2bf(a[i]); return; }
    i -= na;
    if (i < nb) { db[i] = f2bf(b2[i]); return; }
    i -= nb;
    if (i < nc) { dc[i] = f2bf(c[i]); return; }
    i -= nc;
    dd[i] = f2bf(d[i]);
}

// ---------------- head transpose: w[4][512][1024] f32 -> wt[4][1024][512] bf16 ----------------
__global__ __launch_bounds__(256) void ht_k(const float* __restrict__ w, u16* __restrict__ wt) {
    __shared__ float tile[64][65];
    int z = blockIdx.z;
    int v0 = blockIdx.x << 6, d0 = blockIdx.y << 6;
    int col = threadIdx.x & 63, rbase = threadIdx.x >> 6;
#pragma unroll
    for (int i = 0; i < 16; i++) {
        int row = (i << 2) + rbase;  // d-local
        tile[row][col] = w[(ll)z * (DM * V_SZ) + (ll)(d0 + row) * V_SZ + v0 + col];
    }
    __syncthreads();
#pragma unroll
    for (int i = 0; i < 16; i++) {
        int vrow = (i << 2) + rbase; // v-local
        wt[(ll)z * (V_SZ * DM) + (ll)(v0 + vrow) * DM + d0 + col] = f2bf(tile[col][vrow]);
    }
}

// ---------------- flat f32 -> bf16 ----------------
__global__ __launch_bounds__(256) void cvt_k(const float* __restrict__ s, u16* __restrict__ d) {
    int i = blockIdx.x * 256 + threadIdx.x;
    d[i] = f2bf(s[i]);
}

// ---------------- embedding ----------------
__global__ __launch_bounds__(512) void embed_k(const int* __restrict__ codes,
                                               const float* __restrict__ ew,
                                               float* __restrict__ x) {
    int row = blockIdx.x;  // b*1024 + t
    int b = row >> 10, t = row & 1023;
    int d = threadIdx.x;
    float acc = 0.f;
#pragma unroll
    for (int k = 0; k < K_CB; k++) {
        int c = codes[b * (K_CB * T_SZ) + k * T_SZ + t];
        acc += ew[((ll)k * V_SZ + c) * DM + d];
    }
    x[(ll)row * DM + d] = acc;
}

// ---------------- rmsnorm: f32 in -> bf16 out ----------------
__global__ __launch_bounds__(256) void rmsnorm_k(const float* __restrict__ x,
                                                 const float* __restrict__ w,
                                                 u16* __restrict__ xn) {
    ll row = blockIdx.x;
    const float* xr = x + row * DM;
    int tid = threadIdx.x;
    float v0 = xr[tid], v1 = xr[tid + 256];
    float ss = v0 * v0 + v1 * v1;
#pragma unroll
    for (int off = 32; off > 0; off >>= 1) ss += __shfl_down(ss, off, 64);
    __shared__ float red[4];
    if ((tid & 63) == 0) red[tid >> 6] = ss;
    __syncthreads();
    float tot = red[0] + red[1] + red[2] + red[3];
    float scale = rsqrtf(tot * (1.0f / DM) + 1e-6f);
    xn[row * DM + tid]       = f2bf(v0 * scale * w[tid]);
    xn[row * DM + tid + 256] = f2bf(v1 * scale * w[tid + 256]);
}

// ---------------- bf16 MFMA GEMM: C[M,N] = A[M,K](bf16) * W[N,K](bf16)^T ----------------
// 64x64 tile, BK=32, 4 waves in 2x2, each wave 2x2 mfma 16x16x32 tiles.
// EP: 0 = bf16 store Cb (in_proj->xz_bf), 1 = f32 store C (x_proj),
//     2 = softplus(acc+bias[n]) f32 (dt_proj), 3 = C += acc & Cb=bf16(C) (out_proj),
//     4 = head scatter f32 (blockIdx.z = codebook)
template <int EP>
__global__ __launch_bounds__(256) void mgemm_k(const u16* __restrict__ A, int lda,
                                               const u16* __restrict__ W,
                                               float* __restrict__ C, int ldc, int K,
                                               const float* __restrict__ bias,
                                               u16* __restrict__ Cb, int ldcb) {
    __shared__ u16 As[64][40];
    __shared__ u16 Bs[64][40];
    int tid = threadIdx.x;
    int m0 = blockIdx.y << 6, n0 = blockIdx.x << 6;
    if (EP == 4) W += (ll)blockIdx.z * (V_SZ * DM);
    int lane = tid & 63, wave = tid >> 6;
    int q = lane >> 4, r = lane & 15;
    int wm = (wave >> 1) << 5, wn = (wave & 1) << 5;
    int srow = tid >> 2, sseg = (tid & 3) << 3;
    f32x4 acc[2][2];
#pragma unroll
    for (int i = 0; i < 2; i++)
#pragma unroll
        for (int j = 0; j < 2; j++) acc[i][j] = (f32x4){0.f, 0.f, 0.f, 0.f};

    for (int k0 = 0; k0 < K; k0 += 32) {
        *(uint4*)&As[srow][sseg] = *(const uint4*)&A[(ll)(m0 + srow) * lda + k0 + sseg];
        *(uint4*)&Bs[srow][sseg] = *(const uint4*)&W[(ll)(n0 + srow) * K + k0 + sseg];
        __syncthreads();
        short8 af[2], bfr[2];
#pragma unroll
        for (int i = 0; i < 2; i++) af[i]  = *(const short8*)&As[wm + (i << 4) + r][q << 3];
#pragma unroll
        for (int j = 0; j < 2; j++) bfr[j] = *(const short8*)&Bs[wn + (j << 4) + r][q << 3];
#pragma unroll
        for (int i = 0; i < 2; i++)
#pragma unroll
            for (int j = 0; j < 2; j++)
                acc[i][j] = __builtin_amdgcn_mfma_f32_16x16x32_bf16(af[i], bfr[j], acc[i][j], 0, 0, 0);
        __syncthreads();
    }

#pragma unroll
    for (int i = 0; i < 2; i++)
#pragma unroll
        for (int j = 0; j < 2; j++)
#pragma unroll
            for (int g = 0; g < 4; g++) {
                int m = m0 + wm + (i << 4) + (q << 2) + g;
                int n = n0 + wn + (j << 4) + r;
                float v = acc[i][j][g];
                if (EP == 0) {
                    Cb[(ll)m * ldcb + n] = f2bf(v);
                } else if (EP == 1) {
                    C[(ll)m * ldc + n] = v;
                } else if (EP == 2) {
                    C[(ll)m * ldc + n] = softplusf(v + bias[n]);
                } else if (EP == 3) {
                    float nv = C[(ll)m * ldc + n] + v;
                    C[(ll)m * ldc + n] = nv;
                    Cb[(ll)m * ldcb + n] = f2bf(nv);
                } else {
                    int b = m >> 10, t = m & 1023;
                    C[(ll)b * (K_CB * (ll)T_SZ * V_SZ) + (ll)blockIdx.z * (T_SZ * V_SZ)
                      + (ll)t * V_SZ + n] = v;
                }
            }
}

// ---------------- causal dwconv(4) + bias + silu: bf16 in, f32 + bf16 out ----------------
__global__ __launch_bounds__(256) void conv_k(const u16* __restrict__ xzb,
                                              const float* __restrict__ cw,
                                              const float* __restrict__ cb,
                                              float* __restrict__ xc,
                                              u16* __restrict__ xcb) {
    int row = blockIdx.x;  // b*1024+t
    int b = row >> 10, t = row & 1023;
    for (int c = threadIdx.x; c < DI; c += 256) {
        float acc = cb[c];
#pragma unroll
        for (int j = 0; j < 4; j++) {
            int tt = t - 3 + j;
            if (tt >= 0)
                acc += bf2f(xzb[((ll)(b * T_SZ + tt)) * (2 * DI) + c]) * cw[c * 4 + j];
        }
        float s = siluf(acc);
        xc[(ll)row * DI + c] = s;
        xcb[(ll)row * DI + c] = f2bf(s);
    }
}

// ---------------- chunked selective scan ----------------
// pass 1: per-chunk (prodA, U). grid = B*NCHUNK*(DI/256) = 512 blocks
__global__ __launch_bounds__(256) void scan1_k(const float* __restrict__ dt,
                                               const float* __restrict__ xc,
                                               const float* __restrict__ xdbl,
                                               const float* __restrict__ A_log,
                                               float* __restrict__ pA, float* __restrict__ U) {
    int blk = blockIdx.x;
    int dblk = blk & 3;
    int c = (blk >> 2) & (NCHUNK - 1);
    int b = blk >> 8;
    int d = dblk * 256 + threadIdx.x;
    float Av[NS];
#pragma unroll
    for (int n = 0; n < NS; n++) Av[n] = -__expf(A_log[d * NS + n]);
    float p[NS], u[NS];
#pragma unroll
    for (int n = 0; n < NS; n++) { p[n] = 1.f; u[n] = 0.f; }
    int t0 = c * TCHUNK;
    for (int s = 0; s < TCHUNK; s++) {
        ll ro = (ll)b * T_SZ + t0 + s;
        float dtv = dt[ro * DI + d];
        float xv = xc[ro * DI + d];
        float dx = dtv * xv;
        const float* Brow = xdbl + ro * 64 + DTR;
#pragma unroll
        for (int n = 0; n < NS; n++) {
            float a = __expf(dtv * Av[n]);
            p[n] *= a;
            u[n] = fmaf(a, u[n], dx * Brow[n]);
        }
    }
    ll o = (((ll)b * NCHUNK + c) * DI + d) * NS;
#pragma unroll
    for (int n = 0; n < NS; n++) { pA[o + n] = p[n]; U[o + n] = u[n]; }
}

// pass 2: combine over chunks; hst may alias U (read U before write)
__global__ __launch_bounds__(256) void scan2_k(const float* __restrict__ pA,
                                               const float* __restrict__ U,
                                               float* __restrict__ hst) {
    int i = blockIdx.x * 256 + threadIdx.x;  // b*(DI*NS) + d*NS + n
    int b = i >> 14;
    int rest = i & 16383;
    float h = 0.f;
#pragma unroll
    for (int c = 0; c < NCHUNK; c++) {
        ll o = ((ll)b * NCHUNK + c) * (DI * NS) + rest;
        float pa = pA[o], u = U[o];
        hst[o] = h;
        h = fmaf(pa, h, u);
    }
}

// pass 3: replay with true initial h; fuse D_skip + silu(z) gate; bf16 y out
__global__ __launch_bounds__(256) void scan3_k(const float* __restrict__ dt,
                                               const float* __restrict__ xc,
                                               const float* __restrict__ xdbl,
                                               const u16* __restrict__ xzb,
                                               const float* __restrict__ A_log,
                                               const float* __restrict__ Dk,
                                               const float* __restrict__ hst,
                                               u16* __restrict__ y) {
    int blk = blockIdx.x;
    int dblk = blk & 3;
    int c = (blk >> 2) & (NCHUNK - 1);
    int b = blk >> 8;
    int d = dblk * 256 + threadIdx.x;
    float Av[NS];
#pragma unroll
    for (int n = 0; n < NS; n++) Av[n] = -__expf(A_log[d * NS + n]);
    float h[NS];
    ll ho = (((ll)b * NCHUNK + c) * DI + d) * NS;
#pragma unroll
    for (int n = 0; n < NS; n++) h[n] = hst[ho + n];
    float Dv = Dk[d];
    int t0 = c * TCHUNK;
    for (int s = 0; s < TCHUNK; s++) {
        ll ro = (ll)b * T_SZ + t0 + s;
        float dtv = dt[ro * DI + d];
        float xv = xc[ro * DI + d];
        float dx = dtv * xv;
        const float* Brow = xdbl + ro * 64 + DTR;
        const float* Crow = xdbl + ro * 64 + DTR + NS;
        float acc = 0.f;
#pragma unroll
        for (int n = 0; n < NS; n++) {
            float a = __expf(dtv * Av[n]);
            h[n] = fmaf(a, h[n], dx * Brow[n]);
            acc = fmaf(h[n], Crow[n], acc);
        }
        float zv = bf2f(xzb[ro * (2 * DI) + DI + d]);
        y[ro * DI + d] = f2bf((acc + xv * Dv) * siluf(zv));
    }
}

extern "C" void kernel_launch(void* const* d_in, const int* in_sizes, int n_in,
                              void* d_out, int out_size, void* d_ws, size_t ws_size,
                              hipStream_t stream) {
    const int*   codes   = (const int*)d_in[0];
    const float* embed_w = (const float*)d_in[1];
    const float* norm_w  = (const float*)d_in[2];
    const float* in_w    = (const float*)d_in[3];
    const float* conv_w  = (const float*)d_in[4];
    const float* conv_b  = (const float*)d_in[5];
    const float* xp_w    = (const float*)d_in[6];
    const float* dtp_w   = (const float*)d_in[7];
    const float* dtp_b   = (const float*)d_in[8];
    const float* A_log   = (const float*)d_in[9];
    const float* D_skip  = (const float*)d_in[10];
    const float* out_w   = (const float*)d_in[11];
    const float* head_w  = (const float*)d_in[12];
    float* out = (float*)d_out;

    float* ws = (float*)d_ws;
    float* x    = ws;                  // 1,048,576 f32
    float* xc   = x + 1048576;         // 2,097,152
    float* dtb  = xc + 2097152;        // 2,097,152
    float* xdbl = dtb + 2097152;       // 131,072
    float* pA   = xdbl + 131072;       // 2,097,152 (B*NCHUNK*DI*NS)
    float* Uh   = pA + 2097152;        // 2,097,152 (U, then hst in-place)

    u16* us       = (u16*)(Uh + 2097152);
    u16* xz_bf    = us;                 // 4,194,304 (2048 x 2048)
    u16* xc_bf    = xz_bf + 4194304;    // 2,097,152 (also hosts x_bf: first 1M, disjoint lifetime)
    u16* ybxn_bf  = xc_bf + 2097152;    // 2,097,152 (y_bf full; xn_bf shares first 1M)
    u16* xdbl_bf  = ybxn_bf + 2097152;  // 131,072
    u16* w_in_bf  = xdbl_bf + 131072;   // 2,097,152
    u16* w_xp_bf  = w_in_bf + 2097152;  // 131,072
    u16* w_dt_bf  = w_xp_bf + 131072;   // 65,536
    u16* w_out_bf = w_dt_bf + 65536;    // 1,048,576
    u16* w_hd_bf  = w_out_bf + 1048576; // 2,097,152   total ~66 MB

    u16* xn_bf = ybxn_bf;
    u16* y_bf  = ybxn_bf;
    u16* x_bf  = xc_bf;

    const int M = B_SZ * T_SZ;  // 2048

    // weights -> bf16 (once per launch; inputs restored every call)
    wcvt_k<<<13056, 256, 0, stream>>>(in_w, w_in_bf, 2097152,
                                      xp_w, w_xp_bf, 131072,
                                      dtp_w, w_dt_bf, 65536,
                                      out_w, w_out_bf);
    ht_k<<<dim3(16, 8, 4), 256, 0, stream>>>(head_w, w_hd_bf);

    embed_k<<<M, 512, 0, stream>>>(codes, embed_w, x);

    for (int l = 0; l < 2; l++) {
        const float* al = A_log + l * DI * NS;
        rmsnorm_k<<<M, 256, 0, stream>>>(x, norm_w + l * DM, xn_bf);
        // xz = xn @ in_w^T : (2048 x 2048), K=512 -> bf16
        mgemm_k<0><<<dim3(32, 32), 256, 0, stream>>>(xn_bf, DM, w_in_bf + l * 1048576,
                                                     nullptr, 0, DM, nullptr, xz_bf, 2 * DI);
        conv_k<<<M, 256, 0, stream>>>(xz_bf, conv_w + l * DI * 4, conv_b + l * DI, xc, xc_bf);
        // x_dbl = xc @ xp_w^T : (2048 x 64), K=1024 -> f32
        mgemm_k<1><<<dim3(1, 32), 256, 0, stream>>>(xc_bf, DI, w_xp_bf + l * 65536,
                                                    xdbl, 64, DI, nullptr, nullptr, 0);
        cvt_k<<<512, 256, 0, stream>>>(xdbl, xdbl_bf);
        // dt = softplus(x_dbl[:, :32] @ dtp_w^T + b) : (2048 x 1024), K=32
        mgemm_k<2><<<dim3(16, 32), 256, 0, stream>>>(xdbl_bf, 64, w_dt_bf + l * 32768,
                                                     dtb, DI, DTR, dtp_b + l * DI, nullptr, 0);
        scan1_k<<<512, 256, 0, stream>>>(dtb, xc, xdbl, al, pA, Uh);
        scan2_k<<<128, 256, 0, stream>>>(pA, Uh, Uh);
        scan3_k<<<512, 256, 0, stream>>>(dtb, xc, xdbl, xz_bf, al, D_skip + l * DI, Uh, y_bf);
        // x += y @ out_w^T : (2048 x 512), K=1024; also x_bf = bf16(x)
        mgemm_k<3><<<dim3(8, 32), 256, 0, stream>>>(y_bf, DI, w_out_bf + l * 524288,
                                                    x, DM, DI, nullptr, x_bf, DM);
    }

    // head: out[b,z,t,v] = x[b,t,:] @ head_w[z]  (w_hd_bf is [z][v][d]); one 3D dispatch
    mgemm_k<4><<<dim3(16, 32, 4), 256, 0, stream>>>(x_bf, DM, w_hd_bf,
                                                    out, 0, DM, nullptr, nullptr, 0);
}

// Round 5
// 334.046 us; speedup vs baseline: 2.6711x; 1.0449x over previous
//
#include <hip/hip_runtime.h>
#include <hip/hip_bf16.h>

// MambaLM: B=2,K=4,T=1024,V=1024, d_model=512, d_inner=1024, N=16, dt_rank=32, L=2
// R5: (1) 128x128 global_load_lds MFMA GEMM (m97 structure) for in_proj + head;
//     (2) scan1/scan3 stage B/C rows in LDS (kill 32 broadcast VMEM/step);
//     (3) fuse embed+rmsnorm, cvt->x_proj epilogue, vectorized conv + wcvt.

#define B_SZ 2
#define K_CB 4
#define T_SZ 1024
#define V_SZ 1024
#define DM 512
#define DI 1024
#define NS 16
#define DTR 32
#define NCHUNK 64
#define TCHUNK 16

typedef unsigned short u16;
typedef long long ll;
using short8 = __attribute__((ext_vector_type(8))) short;
using f32x4  = __attribute__((ext_vector_type(4))) float;

__device__ __forceinline__ float bf2f(u16 u) {
    union { unsigned int i; float f; } v; v.i = ((unsigned int)u) << 16; return v.f;
}
__device__ __forceinline__ u16 f2bf(float f) {
    union { float f; unsigned int i; } v; v.f = f;
    unsigned int x = v.i;
    return (u16)((x + 0x7fffu + ((x >> 16) & 1u)) >> 16);
}
__device__ __forceinline__ float siluf(float x) { return x / (1.f + __expf(-x)); }
__device__ __forceinline__ float softplusf(float x) { return (x > 20.f) ? x : log1pf(__expf(x)); }

__device__ __forceinline__ void gld16(const void* g, void* l) {
    __builtin_amdgcn_global_load_lds(
        (const __attribute__((address_space(1))) unsigned int*)g,
        (__attribute__((address_space(3))) unsigned int*)l, 16, 0, 0);
}

// ---------------- weight bf16 conversion, float4 per thread ----------------
__global__ __launch_bounds__(256) void wcvt4_k(const float* __restrict__ in_w,
                                               const float* __restrict__ xp_w,
                                               const float* __restrict__ dtp_w,
                                               const float* __restrict__ out_w,
                                               u16* __restrict__ w_in, u16* __restrict__ w_xp,
                                               u16* __restrict__ w_dt, u16* __restrict__ w_out) {
    int i = (blockIdx.x * 256 + threadIdx.x) << 2;
    const float* s; u16* d;
    if (i < 2097152) { s = in_w + i; d = w_in + i; }
    else {
        i -= 2097152;
        if (i < 131072) { s = xp_w + i; d = w_xp + i; }
        else {
            i -= 131072;
            if (i < 65536) { s = dtp_w + i; d = w_dt + i; }
            else { i -= 65536; s = out_w + i; d = w_out + i; }
        }
    }
    float4 v = *(const float4*)s;
    ushort4 o; o.x = f2bf(v.x); o.y = f2bf(v.y); o.z = f2bf(v.z); o.w = f2bf(v.w);
    *(ushort4*)d = o;
}

// ---------------- head transpose: w[4][512][1024] f32 -> wt[4][1024][512] bf16 ----------------
__global__ __launch_bounds__(256) void ht_k(const float* __restrict__ w, u16* __restrict__ wt) {
    __shared__ float tile[64][65];
    int z = blockIdx.z;
    int v0 = blockIdx.x << 6, d0 = blockIdx.y << 6;
    int col = threadIdx.x & 63, rbase = threadIdx.x >> 6;
#pragma unroll
    for (int i = 0; i < 16; i++) {
        int row = (i << 2) + rbase;
        tile[row][col] = w[(ll)z * (DM * V_SZ) + (ll)(d0 + row) * V_SZ + v0 + col];
    }
    __syncthreads();
#pragma unroll
    for (int i = 0; i < 16; i++) {
        int vrow = (i << 2) + rbase;
        wt[(ll)z * (V_SZ * DM) + (ll)(v0 + vrow) * DM + d0 + col] = f2bf(tile[col][vrow]);
    }
}

// ---------------- embedding + rmsnorm fused (layer 0 input) ----------------
__global__ __launch_bounds__(512) void embrms_k(const int* __restrict__ codes,
                                                const float* __restrict__ ew,
                                                const float* __restrict__ nw,
                                                float* __restrict__ x,
                                                u16* __restrict__ xn) {
    int row = blockIdx.x;  // b*1024 + t
    int b = row >> 10, t = row & 1023;
    int d = threadIdx.x;
    float acc = 0.f;
#pragma unroll
    for (int k = 0; k < K_CB; k++) {
        int c = codes[b * (K_CB * T_SZ) + k * T_SZ + t];
        acc += ew[((ll)k * V_SZ + c) * DM + d];
    }
    x[(ll)row * DM + d] = acc;
    float ss = acc * acc;
#pragma unroll
    for (int off = 32; off > 0; off >>= 1) ss += __shfl_down(ss, off, 64);
    __shared__ float red[8];
    if ((d & 63) == 0) red[d >> 6] = ss;
    __syncthreads();
    float tot = red[0] + red[1] + red[2] + red[3] + red[4] + red[5] + red[6] + red[7];
    float scale = rsqrtf(tot * (1.0f / DM) + 1e-6f);
    xn[(ll)row * DM + d] = f2bf(acc * scale * nw[d]);
}

// ---------------- rmsnorm (layer 1): f32 in -> bf16 out ----------------
__global__ __launch_bounds__(256) void rmsnorm_k(const float* __restrict__ x,
                                                 const float* __restrict__ w,
                                                 u16* __restrict__ xn) {
    ll row = blockIdx.x;
    const float* xr = x + row * DM;
    int tid = threadIdx.x;
    float v0 = xr[tid], v1 = xr[tid + 256];
    float ss = v0 * v0 + v1 * v1;
#pragma unroll
    for (int off = 32; off > 0; off >>= 1) ss += __shfl_down(ss, off, 64);
    __shared__ float red[4];
    if ((tid & 63) == 0) red[tid >> 6] = ss;
    __syncthreads();
    float tot = red[0] + red[1] + red[2] + red[3];
    float scale = rsqrtf(tot * (1.0f / DM) + 1e-6f);
    xn[row * DM + tid]       = f2bf(v0 * scale * w[tid]);
    xn[row * DM + tid + 256] = f2bf(v1 * scale * w[tid + 256]);
}

// ---------------- 128x128 MFMA GEMM, global_load_lds staging (m97 structure) ----------------
// C[M,N] = A[M,K](bf16) * W[N,K](bf16)^T.  4 waves in 2x2, each wave 64x64 = 4x4 mfma tiles.
// EP: 0 = bf16 store Cb (in_proj), 4 = head f32 scatter (blockIdx.z = codebook)
template <int EP>
__global__ __launch_bounds__(256) void mgemm2_k(const u16* __restrict__ A, int lda,
                                                const u16* __restrict__ W,
                                                float* __restrict__ C,
                                                u16* __restrict__ Cb, int ldcb, int K) {
    __shared__ u16 As[4096];   // [128][32]
    __shared__ u16 Bs[4096];
    int tid = threadIdx.x;
    int wave = tid >> 6, lane = tid & 63;
    int q = lane >> 4, r = lane & 15;
    int m0 = blockIdx.y << 7, n0 = blockIdx.x << 7;
    const u16* Wz = W;
    if (EP == 4) Wz += (ll)blockIdx.z * ((ll)V_SZ * DM);
    int wm = (wave >> 1) << 6, wn = (wave & 1) << 6;
    int sa0 = (wave << 7) + lane, sa1 = sa0 + 64;   // staging slots (row=s>>2, chunk=s&3)
    f32x4 acc[4][4];
#pragma unroll
    for (int i = 0; i < 4; i++)
#pragma unroll
        for (int j = 0; j < 4; j++) acc[i][j] = (f32x4){0.f, 0.f, 0.f, 0.f};

    for (int k0 = 0; k0 < K; k0 += 32) {
        gld16(A  + (ll)(m0 + (sa0 >> 2)) * lda + k0 + ((sa0 & 3) << 3), &As[wave << 10]);
        gld16(A  + (ll)(m0 + (sa1 >> 2)) * lda + k0 + ((sa1 & 3) << 3), &As[(wave << 10) + 512]);
        gld16(Wz + (ll)(n0 + (sa0 >> 2)) * K   + k0 + ((sa0 & 3) << 3), &Bs[wave << 10]);
        gld16(Wz + (ll)(n0 + (sa1 >> 2)) * K   + k0 + ((sa1 & 3) << 3), &Bs[(wave << 10) + 512]);
        __syncthreads();
        short8 af[4], bfr[4];
#pragma unroll
        for (int i = 0; i < 4; i++) af[i]  = *(const short8*)&As[((wm + (i << 4) + r) << 5) + (q << 3)];
#pragma unroll
        for (int j = 0; j < 4; j++) bfr[j] = *(const short8*)&Bs[((wn + (j << 4) + r) << 5) + (q << 3)];
#pragma unroll
        for (int i = 0; i < 4; i++)
#pragma unroll
            for (int j = 0; j < 4; j++)
                acc[i][j] = __builtin_amdgcn_mfma_f32_16x16x32_bf16(af[i], bfr[j], acc[i][j], 0, 0, 0);
        __syncthreads();
    }

#pragma unroll
    for (int i = 0; i < 4; i++)
#pragma unroll
        for (int j = 0; j < 4; j++)
#pragma unroll
            for (int g = 0; g < 4; g++) {
                int m = m0 + wm + (i << 4) + (q << 2) + g;
                int n = n0 + wn + (j << 4) + r;
                float v = acc[i][j][g];
                if (EP == 0) {
                    Cb[(ll)m * ldcb + n] = f2bf(v);
                } else {
                    int b = m >> 10, t = m & 1023;
                    C[(ll)b * (K_CB * (ll)T_SZ * V_SZ) + (ll)blockIdx.z * (T_SZ * V_SZ)
                      + (ll)t * V_SZ + n] = v;
                }
            }
}

// ---------------- 64x64 MFMA GEMM (small shapes) ----------------
// EP: 1 = f32 + bf16 store (x_proj), 2 = softplus(acc+bias[n]) f32 (dt_proj),
//     3 = C += acc & Cb=bf16(C) (out_proj)
template <int EP>
__global__ __launch_bounds__(256) void mgemm_k(const u16* __restrict__ A, int lda,
                                               const u16* __restrict__ W,
                                               float* __restrict__ C, int ldc, int K,
                                               const float* __restrict__ bias,
                                               u16* __restrict__ Cb, int ldcb) {
    __shared__ u16 As[64][40];
    __shared__ u16 Bs[64][40];
    int tid = threadIdx.x;
    int m0 = blockIdx.y << 6, n0 = blockIdx.x << 6;
    int lane = tid & 63, wave = tid >> 6;
    int q = lane >> 4, r = lane & 15;
    int wm = (wave >> 1) << 5, wn = (wave & 1) << 5;
    int srow = tid >> 2, sseg = (tid & 3) << 3;
    f32x4 acc[2][2];
#pragma unroll
    for (int i = 0; i < 2; i++)
#pragma unroll
        for (int j = 0; j < 2; j++) acc[i][j] = (f32x4){0.f, 0.f, 0.f, 0.f};

    for (int k0 = 0; k0 < K; k0 += 32) {
        *(uint4*)&As[srow][sseg] = *(const uint4*)&A[(ll)(m0 + srow) * lda + k0 + sseg];
        *(uint4*)&Bs[srow][sseg] = *(const uint4*)&W[(ll)(n0 + srow) * K + k0 + sseg];
        __syncthreads();
        short8 af[2], bfr[2];
#pragma unroll
        for (int i = 0; i < 2; i++) af[i]  = *(const short8*)&As[wm + (i << 4) + r][q << 3];
#pragma unroll
        for (int j = 0; j < 2; j++) bfr[j] = *(const short8*)&Bs[wn + (j << 4) + r][q << 3];
#pragma unroll
        for (int i = 0; i < 2; i++)
#pragma unroll
            for (int j = 0; j < 2; j++)
                acc[i][j] = __builtin_amdgcn_mfma_f32_16x16x32_bf16(af[i], bfr[j], acc[i][j], 0, 0, 0);
        __syncthreads();
    }

#pragma unroll
    for (int i = 0; i < 2; i++)
#pragma unroll
        for (int j = 0; j < 2; j++)
#pragma unroll
            for (int g = 0; g < 4; g++) {
                int m = m0 + wm + (i << 4) + (q << 2) + g;
                int n = n0 + wn + (j << 4) + r;
                float v = acc[i][j][g];
                if (EP == 1) {
                    C[(ll)m * ldc + n] = v;
                    Cb[(ll)m * ldcb + n] = f2bf(v);
                } else if (EP == 2) {
                    C[(ll)m * ldc + n] = softplusf(v + bias[n]);
                } else {
                    float nv = C[(ll)m * ldc + n] + v;
                    C[(ll)m * ldc + n] = nv;
                    Cb[(ll)m * ldcb + n] = f2bf(nv);
                }
            }
}

// ---------------- causal dwconv(4) + bias + silu, ushort4-vectorized ----------------
__global__ __launch_bounds__(256) void conv_k(const u16* __restrict__ xzb,
                                              const float* __restrict__ cw,
                                              const float* __restrict__ cb,
                                              float* __restrict__ xc,
                                              u16* __restrict__ xcb) {
    int row = blockIdx.x;  // b*1024+t
    int b = row >> 10, t = row & 1023;
    int c0 = threadIdx.x << 2;
    float4 a = *(const float4*)&cb[c0];
    float acc[4] = {a.x, a.y, a.z, a.w};
    float4 cwv[4];
#pragma unroll
    for (int e = 0; e < 4; e++) cwv[e] = *(const float4*)&cw[(c0 + e) << 2];
#pragma unroll
    for (int j = 0; j < 4; j++) {
        int tt = t - 3 + j;
        if (tt >= 0) {
            ushort4 v = *(const ushort4*)&xzb[((ll)(b * T_SZ + tt)) * (2 * DI) + c0];
            acc[0] = fmaf(bf2f(v.x), ((const float*)&cwv[0])[j], acc[0]);
            acc[1] = fmaf(bf2f(v.y), ((const float*)&cwv[1])[j], acc[1]);
            acc[2] = fmaf(bf2f(v.z), ((const float*)&cwv[2])[j], acc[2]);
            acc[3] = fmaf(bf2f(v.w), ((const float*)&cwv[3])[j], acc[3]);
        }
    }
    float4 s; ushort4 sb;
    s.x = siluf(acc[0]); s.y = siluf(acc[1]); s.z = siluf(acc[2]); s.w = siluf(acc[3]);
    sb.x = f2bf(s.x); sb.y = f2bf(s.y); sb.z = f2bf(s.z); sb.w = f2bf(s.w);
    *(float4*)&xc[(ll)row * DI + c0] = s;
    *(ushort4*)&xcb[(ll)row * DI + c0] = sb;
}

// ---------------- chunked selective scan ----------------
// pass 1: per-chunk (prodA, U). grid = B*NCHUNK*(DI/256) = 512 blocks
__global__ __launch_bounds__(256) void scan1_k(const float* __restrict__ dt,
                                               const float* __restrict__ xc,
                                               const float* __restrict__ xdbl,
                                               const float* __restrict__ A_log,
                                               float* __restrict__ pA, float* __restrict__ U) {
    int blk = blockIdx.x;
    int dblk = blk & 3;
    int c = (blk >> 2) & (NCHUNK - 1);
    int b = blk >> 8;
    int d = dblk * 256 + threadIdx.x;
    int t0 = c * TCHUNK;
    __shared__ float BC[TCHUNK][32];
    if (threadIdx.x < TCHUNK * 8) {
        int rr = threadIdx.x >> 3, cc = (threadIdx.x & 7) << 2;
        *(float4*)&BC[rr][cc] = *(const float4*)&xdbl[((ll)(b * T_SZ + t0 + rr)) * 64 + DTR + cc];
    }
    float Av[NS];
#pragma unroll
    for (int n4 = 0; n4 < 4; n4++) {
        float4 alv = *(const float4*)&A_log[d * NS + (n4 << 2)];
        Av[(n4 << 2) + 0] = -__expf(alv.x); Av[(n4 << 2) + 1] = -__expf(alv.y);
        Av[(n4 << 2) + 2] = -__expf(alv.z); Av[(n4 << 2) + 3] = -__expf(alv.w);
    }
    __syncthreads();
    float p[NS], u[NS];
#pragma unroll
    for (int n = 0; n < NS; n++) { p[n] = 1.f; u[n] = 0.f; }
#pragma unroll
    for (int s = 0; s < TCHUNK; s++) {
        ll ro = (ll)(b * T_SZ + t0 + s);
        float dtv = dt[ro * DI + d];
        float xv = xc[ro * DI + d];
        float dx = dtv * xv;
#pragma unroll
        for (int n = 0; n < NS; n++) {
            float a = __expf(dtv * Av[n]);
            p[n] *= a;
            u[n] = fmaf(a, u[n], dx * BC[s][n]);
        }
    }
    ll o = (((ll)b * NCHUNK + c) * DI + d) * NS;
#pragma unroll
    for (int n = 0; n < NS; n++) { pA[o + n] = p[n]; U[o + n] = u[n]; }
}

// pass 2: combine over chunks; hst aliases U (read U before write)
__global__ __launch_bounds__(256) void scan2_k(const float* __restrict__ pA,
                                               const float* __restrict__ U,
                                               float* __restrict__ hst) {
    int i = blockIdx.x * 256 + threadIdx.x;  // b*(DI*NS) + d*NS + n
    int b = i >> 14;
    int rest = i & 16383;
    float h = 0.f;
#pragma unroll
    for (int c = 0; c < NCHUNK; c++) {
        ll o = ((ll)b * NCHUNK + c) * (DI * NS) + rest;
        float pa = pA[o], u = U[o];
        hst[o] = h;
        h = fmaf(pa, h, u);
    }
}

// pass 3: replay with true initial h; fuse D_skip + silu(z) gate; bf16 y out
__global__ __launch_bounds__(256) void scan3_k(const float* __restrict__ dt,
                                               const float* __restrict__ xc,
                                               const float* __restrict__ xdbl,
                                               const u16* __restrict__ xzb,
                                               const float* __restrict__ A_log,
                                               const float* __restrict__ Dk,
                                               const float* __restrict__ hst,
                                               u16* __restrict__ y) {
    int blk = blockIdx.x;
    int dblk = blk & 3;
    int c = (blk >> 2) & (NCHUNK - 1);
    int b = blk >> 8;
    int d = dblk * 256 + threadIdx.x;
    int t0 = c * TCHUNK;
    __shared__ float BC[TCHUNK][32];
    if (threadIdx.x < TCHUNK * 8) {
        int rr = threadIdx.x >> 3, cc = (threadIdx.x & 7) << 2;
        *(float4*)&BC[rr][cc] = *(const float4*)&xdbl[((ll)(b * T_SZ + t0 + rr)) * 64 + DTR + cc];
    }
    float Av[NS];
#pragma unroll
    for (int n4 = 0; n4 < 4; n4++) {
        float4 alv = *(const float4*)&A_log[d * NS + (n4 << 2)];
        Av[(n4 << 2) + 0] = -__expf(alv.x); Av[(n4 << 2) + 1] = -__expf(alv.y);
        Av[(n4 << 2) + 2] = -__expf(alv.z); Av[(n4 << 2) + 3] = -__expf(alv.w);
    }
    float h[NS];
    ll ho = (((ll)b * NCHUNK + c) * DI + d) * NS;
#pragma unroll
    for (int n = 0; n < NS; n++) h[n] = hst[ho + n];
    float Dv = Dk[d];
    __syncthreads();
#pragma unroll
    for (int s = 0; s < TCHUNK; s++) {
        ll ro = (ll)(b * T_SZ + t0 + s);
        float dtv = dt[ro * DI + d];
        float xv = xc[ro * DI + d];
        float dx = dtv * xv;
        float acc = 0.f;
#pragma unroll
        for (int n = 0; n < NS; n++) {
            float a = __expf(dtv * Av[n]);
            h[n] = fmaf(a, h[n], dx * BC[s][n]);
            acc = fmaf(h[n], BC[s][16 + n], acc);
        }
        float zv = bf2f(xzb[ro * (2 * DI) + DI + d]);
        y[ro * DI + d] = f2bf((acc + xv * Dv) * siluf(zv));
    }
}

extern "C" void kernel_launch(void* const* d_in, const int* in_sizes, int n_in,
                              void* d_out, int out_size, void* d_ws, size_t ws_size,
                              hipStream_t stream) {
    const int*   codes   = (const int*)d_in[0];
    const float* embed_w = (const float*)d_in[1];
    const float* norm_w  = (const float*)d_in[2];
    const float* in_w    = (const float*)d_in[3];
    const float* conv_w  = (const float*)d_in[4];
    const float* conv_b  = (const float*)d_in[5];
    const float* xp_w    = (const float*)d_in[6];
    const float* dtp_w   = (const float*)d_in[7];
    const float* dtp_b   = (const float*)d_in[8];
    const float* A_log   = (const float*)d_in[9];
    const float* D_skip  = (const float*)d_in[10];
    const float* out_w   = (const float*)d_in[11];
    const float* head_w  = (const float*)d_in[12];
    float* out = (float*)d_out;

    float* ws = (float*)d_ws;
    float* x    = ws;                  // 1,048,576 f32
    float* xc   = x + 1048576;         // 2,097,152
    float* dtb  = xc + 2097152;        // 2,097,152
    float* xdbl = dtb + 2097152;       // 131,072
    float* pA   = xdbl + 131072;       // 2,097,152
    float* Uh   = pA + 2097152;        // 2,097,152 (U, then hst in-place)

    u16* us       = (u16*)(Uh + 2097152);
    u16* xz_bf    = us;                 // 4,194,304
    u16* xc_bf    = xz_bf + 4194304;    // 2,097,152 (x_bf shares first 1M, disjoint lifetime)
    u16* ybxn_bf  = xc_bf + 2097152;    // 2,097,152 (y_bf full; xn_bf shares first 1M)
    u16* xdbl_bf  = ybxn_bf + 2097152;  // 131,072
    u16* w_in_bf  = xdbl_bf + 131072;   // 2,097,152
    u16* w_xp_bf  = w_in_bf + 2097152;  // 131,072
    u16* w_dt_bf  = w_xp_bf + 131072;   // 65,536
    u16* w_out_bf = w_dt_bf + 65536;    // 1,048,576
    u16* w_hd_bf  = w_out_bf + 1048576; // 2,097,152

    u16* xn_bf = ybxn_bf;
    u16* y_bf  = ybxn_bf;
    u16* x_bf  = xc_bf;

    const int M = B_SZ * T_SZ;  // 2048

    wcvt4_k<<<3264, 256, 0, stream>>>(in_w, xp_w, dtp_w, out_w,
                                      w_in_bf, w_xp_bf, w_dt_bf, w_out_bf);
    ht_k<<<dim3(16, 8, 4), 256, 0, stream>>>(head_w, w_hd_bf);

    embrms_k<<<M, 512, 0, stream>>>(codes, embed_w, norm_w, x, xn_bf);

    for (int l = 0; l < 2; l++) {
        const float* al = A_log + l * DI * NS;
        if (l == 1)
            rmsnorm_k<<<M, 256, 0, stream>>>(x, norm_w + DM, xn_bf);
        // xz = xn @ in_w^T : (2048 x 2048), K=512 -> bf16
        mgemm2_k<0><<<dim3(16, 16), 256, 0, stream>>>(xn_bf, DM, w_in_bf + l * 1048576,
                                                      nullptr, xz_bf, 2 * DI, DM);
        conv_k<<<M, 256, 0, stream>>>(xz_bf, conv_w + l * DI * 4, conv_b + l * DI, xc, xc_bf);
        // x_dbl = xc @ xp_w^T : (2048 x 64), K=1024 -> f32 + bf16
        mgemm_k<1><<<dim3(1, 32), 256, 0, stream>>>(xc_bf, DI, w_xp_bf + l * 65536,
                                                    xdbl, 64, DI, nullptr, xdbl_bf, 64);
        // dt = softplus(x_dbl[:, :32] @ dtp_w^T + b) : (2048 x 1024), K=32
        mgemm_k<2><<<dim3(16, 32), 256, 0, stream>>>(xdbl_bf, 64, w_dt_bf + l * 32768,
                                                     dtb, DI, DTR, dtp_b + l * DI, nullptr, 0);
        scan1_k<<<512, 256, 0, stream>>>(dtb, xc, xdbl, al, pA, Uh);
        scan2_k<<<128, 256, 0, stream>>>(pA, Uh, Uh);
        scan3_k<<<512, 256, 0, stream>>>(dtb, xc, xdbl, xz_bf, al, D_skip + l * DI, Uh, y_bf);
        // x += y @ out_w^T : (2048 x 512), K=1024; also x_bf = bf16(x)
        mgemm_k<3><<<dim3(8, 32), 256, 0, stream>>>(y_bf, DI, w_out_bf + l * 524288,
                                                    x, DM, DI, nullptr, x_bf, DM);
    }

    // head: out[b,z,t,v] = x[b,t,:] @ head_w[z]^T (w_hd_bf is [z][v][d])
    mgemm2_k<4><<<dim3(8, 16, 4), 256, 0, stream>>>(x_bf, DM, w_hd_bf,
                                                    out, nullptr, 0, DM);
}